// Round 2
// baseline (165.302 us; speedup 1.0000x reference)
//
#include <hip/hip_runtime.h>
#include <hip/hip_bf16.h>
#include <math.h>

#define B_ 8
#define N_ 256
#define H_ 128
#define NODES_ (B_ * N_)   // 2048

__device__ __forceinline__ float silu_fast(float x) {
    float e = __expf(-x);
    return x * __builtin_amdgcn_rcpf(1.0f + e);
}

// ---------------------------------------------------------------------------
// k1_fused: weight-stationary. Thread owns one output column's K=128 weights
// in VGPRs; node values are block-uniform -> scalar loads. Produces:
//   g=0: P[n][c]   = node[n]·We1[0:128 ,c] + be1[c]
//   g=1: Q[n][c]   = node[n]·We1[128:256,c]
//   g=2: pre[n][c] = node[n]·Wn1[0:128 ,c] + bn1[c]
// grid 256 (8 nodes/block), block 384 (3 col-groups x 128 cols)
// ---------------------------------------------------------------------------
__global__ __launch_bounds__(384) void k1_fused(
    const float* __restrict__ node, const float* __restrict__ We1,
    const float* __restrict__ be1, const float* __restrict__ Wn1,
    const float* __restrict__ bn1,
    float* __restrict__ P, float* __restrict__ Q, float* __restrict__ pre)
{
    const int t = threadIdx.x;
    const int g = t >> 7;          // wave-uniform (waves are 64 threads)
    const int c = t & 127;
    const int node0 = blockIdx.x * 8;

    const float* Wcol;
    float bias;
    float* op;
    if (g == 0)      { Wcol = We1 + c;              bias = be1[c]; op = P;  }
    else if (g == 1) { Wcol = We1 + 128 * H_ + c;   bias = 0.0f;   op = Q;  }
    else             { Wcol = Wn1 + c;              bias = bn1[c]; op = pre;}

    float w[128];
    #pragma unroll
    for (int k = 0; k < 128; ++k) w[k] = Wcol[k * H_];

    for (int n = 0; n < 8; ++n) {
        const float* __restrict__ vrow = node + (size_t)(node0 + n) * H_;  // uniform
        float a0 = 0.f, a1 = 0.f, a2 = 0.f, a3 = 0.f;
        #pragma unroll
        for (int k = 0; k < 128; k += 4) {
            a0 = fmaf(vrow[k + 0], w[k + 0], a0);
            a1 = fmaf(vrow[k + 1], w[k + 1], a1);
            a2 = fmaf(vrow[k + 2], w[k + 2], a2);
            a3 = fmaf(vrow[k + 3], w[k + 3], a3);
        }
        op[(size_t)(node0 + n) * H_ + c] = (a0 + a1) + (a2 + a3) + bias;
    }
}

// ---------------------------------------------------------------------------
// k2_edge: S[i][c] = sum_j mask_j * silu(P[i][c] + Q[j][c] + d_ij*wd[c])
// grid 512 (4 i-nodes/block), block 256 (c = t&127, j-half = t>>7).
// q loads batched 8-deep so L2 latency hides behind VALU (exp/rcp dominate).
// ---------------------------------------------------------------------------
__global__ __launch_bounds__(256) void k2_edge(
    const float* __restrict__ P, const float* __restrict__ Q,
    const float* __restrict__ We1, const float* __restrict__ positions,
    const float* __restrict__ mask, float* __restrict__ S)
{
    __shared__ float dls[256][4];
    __shared__ float mls[256];
    __shared__ float part[2][4][128];
    const int t  = threadIdx.x;
    const int b  = blockIdx.x >> 6;
    const int i0 = (blockIdx.x & 63) * 4;

    mls[t] = mask[b * N_ + t];
    {
        const int il = t & 3;
        const int jb = t >> 2;
        const float* pb = positions + b * N_ * 3;
        const float pix = pb[(i0 + il) * 3 + 0];
        const float piy = pb[(i0 + il) * 3 + 1];
        const float piz = pb[(i0 + il) * 3 + 2];
        #pragma unroll
        for (int s = 0; s < 4; ++s) {
            int j = jb + 64 * s;
            float dx = pix - pb[j * 3 + 0];
            float dy = piy - pb[j * 3 + 1];
            float dz = piz - pb[j * 3 + 2];
            float sq = dx * dx + dy * dy + dz * dz;
            dls[j][il] = (sq > 0.0f) ? sqrtf(sq) : 0.0f;
        }
    }
    __syncthreads();
    const int c  = t & 127;
    const int jh = t >> 7;
    const float wdc   = We1[256 * H_ + c];
    const float base0 = P[(b * N_ + i0 + 0) * H_ + c];
    const float base1 = P[(b * N_ + i0 + 1) * H_ + c];
    const float base2 = P[(b * N_ + i0 + 2) * H_ + c];
    const float base3 = P[(b * N_ + i0 + 3) * H_ + c];
    float acc0 = 0.f, acc1 = 0.f, acc2 = 0.f, acc3 = 0.f;
    const float* __restrict__ Qb = Q + (b * N_ + jh * 128) * H_ + c;

    for (int jj = 0; jj < 128; jj += 8) {
        float qv[8];
        #pragma unroll
        for (int u = 0; u < 8; ++u) qv[u] = Qb[(jj + u) * H_];
        #pragma unroll
        for (int u = 0; u < 8; ++u) {
            const int j = jh * 128 + jj + u;
            float mj = mls[j];
            float4 d4 = *(const float4*)(&dls[j][0]);
            float x0 = fmaf(d4.x, wdc, base0 + qv[u]);
            float x1 = fmaf(d4.y, wdc, base1 + qv[u]);
            float x2 = fmaf(d4.z, wdc, base2 + qv[u]);
            float x3 = fmaf(d4.w, wdc, base3 + qv[u]);
            acc0 = fmaf(silu_fast(x0), mj, acc0);
            acc1 = fmaf(silu_fast(x1), mj, acc1);
            acc2 = fmaf(silu_fast(x2), mj, acc2);
            acc3 = fmaf(silu_fast(x3), mj, acc3);
        }
    }
    part[jh][0][c] = acc0; part[jh][1][c] = acc1;
    part[jh][2][c] = acc2; part[jh][3][c] = acc3;
    __syncthreads();
    if (t < 128) {
        #pragma unroll
        for (int il = 0; il < 4; ++il)
            S[(b * N_ + i0 + il) * H_ + t] = part[0][il][t] + part[1][il][t];
    }
}

// ---------------------------------------------------------------------------
// kA_agg: agg[n][c] = mask_n*(S[n]·We2[:,c] + cnt*be2[c]) / max(mask_n*cnt,1)
// grid 256 (8 nodes/block), block 128 (one col/thread, weights in VGPRs)
// ---------------------------------------------------------------------------
__global__ __launch_bounds__(128) void kA_agg(
    const float* __restrict__ S, const float* __restrict__ We2,
    const float* __restrict__ be2, const float* __restrict__ mask,
    float* __restrict__ agg)
{
    const int t = threadIdx.x;           // = c
    const int node0 = blockIdx.x * 8;
    const int b  = node0 >> 8;
    const int i0 = node0 & 255;

    float w[128];
    #pragma unroll
    for (int k = 0; k < 128; ++k) w[k] = We2[k * H_ + t];

    // cnt = sum_j mask[b][j]
    float mv = mask[b * N_ + t] + mask[b * N_ + 128 + t];
    #pragma unroll
    for (int off = 32; off >= 1; off >>= 1) mv += __shfl_down(mv, off);
    __shared__ float cs[2];
    if ((t & 63) == 0) cs[t >> 6] = mv;
    __syncthreads();
    const float cnt = cs[0] + cs[1];
    const float bias = be2[t];

    for (int n = 0; n < 8; ++n) {
        const float* __restrict__ vrow = S + (size_t)(node0 + n) * H_;   // uniform
        float a0 = 0.f, a1 = 0.f, a2 = 0.f, a3 = 0.f;
        #pragma unroll
        for (int k = 0; k < 128; k += 4) {
            a0 = fmaf(vrow[k + 0], w[k + 0], a0);
            a1 = fmaf(vrow[k + 1], w[k + 1], a1);
            a2 = fmaf(vrow[k + 2], w[k + 2], a2);
            a3 = fmaf(vrow[k + 3], w[k + 3], a3);
        }
        const float mi  = mask[b * N_ + i0 + n];
        const float inv = mi * __builtin_amdgcn_rcpf(fmaxf(mi * cnt, 1.0f));
        agg[(size_t)(node0 + n) * H_ + t] =
            inv * fmaf(cnt, bias, (a0 + a1) + (a2 + a3));
    }
}

// ---------------------------------------------------------------------------
// kB2_hidden: hidden[n][c] = silu(pre[n][c] + agg[n]·Wn1[128:,c])
// ---------------------------------------------------------------------------
__global__ __launch_bounds__(128) void kB2_hidden(
    const float* __restrict__ agg, const float* __restrict__ pre,
    const float* __restrict__ Wn1, float* __restrict__ hidden)
{
    const int t = threadIdx.x;
    const int node0 = blockIdx.x * 8;

    float w[128];
    #pragma unroll
    for (int k = 0; k < 128; ++k) w[k] = Wn1[(128 + k) * H_ + t];

    for (int n = 0; n < 8; ++n) {
        const float* __restrict__ vrow = agg + (size_t)(node0 + n) * H_;  // uniform
        float a0 = 0.f, a1 = 0.f, a2 = 0.f, a3 = 0.f;
        #pragma unroll
        for (int k = 0; k < 128; k += 4) {
            a0 = fmaf(vrow[k + 0], w[k + 0], a0);
            a1 = fmaf(vrow[k + 1], w[k + 1], a1);
            a2 = fmaf(vrow[k + 2], w[k + 2], a2);
            a3 = fmaf(vrow[k + 3], w[k + 3], a3);
        }
        const size_t idx = (size_t)(node0 + n) * H_ + t;
        hidden[idx] = silu_fast(pre[idx] + (a0 + a1) + (a2 + a3));
    }
}

// ---------------------------------------------------------------------------
// kC_out: out[n][c] = node[n][c] + mask_n*(hidden[n]·Wn2[:,c] + bn2[c])
// ---------------------------------------------------------------------------
__global__ __launch_bounds__(128) void kC_out(
    const float* __restrict__ hidden, const float* __restrict__ node,
    const float* __restrict__ Wn2, const float* __restrict__ bn2,
    const float* __restrict__ mask, float* __restrict__ out)
{
    const int t = threadIdx.x;
    const int node0 = blockIdx.x * 8;
    const int b  = node0 >> 8;
    const int i0 = node0 & 255;

    float w[128];
    #pragma unroll
    for (int k = 0; k < 128; ++k) w[k] = Wn2[k * H_ + t];
    const float bias = bn2[t];

    for (int n = 0; n < 8; ++n) {
        const float* __restrict__ vrow = hidden + (size_t)(node0 + n) * H_; // uniform
        float a0 = 0.f, a1 = 0.f, a2 = 0.f, a3 = 0.f;
        #pragma unroll
        for (int k = 0; k < 128; k += 4) {
            a0 = fmaf(vrow[k + 0], w[k + 0], a0);
            a1 = fmaf(vrow[k + 1], w[k + 1], a1);
            a2 = fmaf(vrow[k + 2], w[k + 2], a2);
            a3 = fmaf(vrow[k + 3], w[k + 3], a3);
        }
        const size_t idx = (size_t)(node0 + n) * H_ + t;
        const float mi = mask[b * N_ + i0 + n];
        out[idx] = node[idx] + mi * ((a0 + a1) + (a2 + a3) + bias);
    }
}

extern "C" void kernel_launch(void* const* d_in, const int* in_sizes, int n_in,
                              void* d_out, int out_size, void* d_ws, size_t ws_size,
                              hipStream_t stream)
{
    const float* node      = (const float*)d_in[0];
    const float* positions = (const float*)d_in[1];
    const float* mask      = (const float*)d_in[2];
    const float* We1       = (const float*)d_in[3];
    const float* be1       = (const float*)d_in[4];
    const float* We2       = (const float*)d_in[5];
    const float* be2       = (const float*)d_in[6];
    const float* Wn1       = (const float*)d_in[7];
    const float* bn1       = (const float*)d_in[8];
    const float* Wn2       = (const float*)d_in[9];
    const float* bn2       = (const float*)d_in[10];
    float* out = (float*)d_out;

    const size_t SZ = (size_t)NODES_ * H_;      // 262144 floats = 1 MB
    float* P      = (float*)d_ws;               // buf0
    float* Q      = P + SZ;                     // buf1
    float* pre    = Q + SZ;                     // buf2
    float* S      = pre + SZ;                   // buf3   (peak ws = 4 MB)
    float* agg    = P;                          // reuse buf0 (P dead after k2)
    float* hidden = Q;                          // reuse buf1 (Q dead after k2)

    k1_fused  <<<NODES_ / 8, 384, 0, stream>>>(node, We1, be1, Wn1, bn1, P, Q, pre);
    k2_edge   <<<NODES_ / 4, 256, 0, stream>>>(P, Q, We1, positions, mask, S);
    kA_agg    <<<NODES_ / 8, 128, 0, stream>>>(S, We2, be2, mask, agg);
    kB2_hidden<<<NODES_ / 8, 128, 0, stream>>>(agg, pre, Wn1, hidden);
    kC_out    <<<NODES_ / 8, 128, 0, stream>>>(hidden, node, Wn2, bn2, mask, out);
}

// Round 3
// 120.157 us; speedup vs baseline: 1.3757x; 1.3757x over previous
//
#include <hip/hip_runtime.h>
#include <hip/hip_bf16.h>
#include <math.h>

#define B_ 8
#define N_ 256
#define H_ 128
#define NODES_ (B_ * N_)   // 2048

__device__ __forceinline__ float silu_fast(float x) {
    float e = __expf(-x);
    return x * __builtin_amdgcn_rcpf(1.0f + e);
}

// Software-pipelined K=128 dot: weight column (stride H_) vs LDS act row
// (broadcast). 8-deep load batches, ping-pong, 2 accumulator chains.
__device__ __forceinline__ float dot128(const float* __restrict__ Wcol,
                                        const float* __restrict__ act)
{
    float wA[8], wB[8];
    #pragma unroll
    for (int u = 0; u < 8; ++u) wA[u] = Wcol[u * H_];
    float acc0 = 0.f, acc1 = 0.f;
    #pragma unroll
    for (int k = 0; k < 128; k += 16) {
        #pragma unroll
        for (int u = 0; u < 8; ++u) wB[u] = Wcol[(k + 8 + u) * H_];
        #pragma unroll
        for (int u = 0; u < 8; u += 2) {
            acc0 = fmaf(act[k + u],     wA[u],     acc0);
            acc1 = fmaf(act[k + u + 1], wA[u + 1], acc1);
        }
        if (k + 16 < 128) {
            #pragma unroll
            for (int u = 0; u < 8; ++u) wA[u] = Wcol[(k + 16 + u) * H_];
        }
        #pragma unroll
        for (int u = 0; u < 8; u += 2) {
            acc0 = fmaf(act[k + 8 + u],     wB[u],     acc0);
            acc1 = fmaf(act[k + 8 + u + 1], wB[u + 1], acc1);
        }
    }
    return acc0 + acc1;
}

// ---------------------------------------------------------------------------
// K1: three [2048x128]x[128x128] GEMMs (P, Q, pre). grid 768 = 3 gemms x 256
// node-tiles (8 nodes). block 256: thread = (node n = t>>5, 4 ch c0=(t&31)*4).
// Vector float4 weight loads, 4-deep ping-pong pipeline; act from LDS.
// ---------------------------------------------------------------------------
__global__ __launch_bounds__(256) void k1(
    const float* __restrict__ node, const float* __restrict__ We1,
    const float* __restrict__ be1, const float* __restrict__ Wn1,
    const float* __restrict__ bn1,
    float* __restrict__ P, float* __restrict__ Q, float* __restrict__ pre)
{
    __shared__ float act[8][128];
    const int t = threadIdx.x;
    const int g = blockIdx.x >> 8;               // 0:P 1:Q 2:pre
    const int node0 = (blockIdx.x & 255) * 8;
    {
        int idx = t * 4;
        int r = idx >> 7, col = idx & 127;
        *(float4*)(&act[r][col]) = *(const float4*)(node + (size_t)(node0 + r) * H_ + col);
    }
    const float* W; const float* bias; float* op;
    if (g == 0)      { W = We1;             bias = be1;     op = P;   }
    else if (g == 1) { W = We1 + 128 * H_;  bias = nullptr; op = Q;   }
    else             { W = Wn1;             bias = bn1;     op = pre; }
    const int n  = t >> 5;
    const int c0 = (t & 31) * 4;
    const float* Wc = W + c0;
    __syncthreads();

    float4 wA[4], wB[4];
    #pragma unroll
    for (int u = 0; u < 4; ++u) wA[u] = *(const float4*)(Wc + u * H_);
    float4 a = {0.f, 0.f, 0.f, 0.f}, b = {0.f, 0.f, 0.f, 0.f};
    #pragma unroll
    for (int k = 0; k < 128; k += 8) {
        #pragma unroll
        for (int u = 0; u < 4; ++u) wB[u] = *(const float4*)(Wc + (k + 4 + u) * H_);
        #pragma unroll
        for (int u = 0; u < 4; u += 2) {
            float v0 = act[n][k + u], v1 = act[n][k + u + 1];
            a.x = fmaf(v0, wA[u].x, a.x);     a.y = fmaf(v0, wA[u].y, a.y);
            a.z = fmaf(v0, wA[u].z, a.z);     a.w = fmaf(v0, wA[u].w, a.w);
            b.x = fmaf(v1, wA[u+1].x, b.x);   b.y = fmaf(v1, wA[u+1].y, b.y);
            b.z = fmaf(v1, wA[u+1].z, b.z);   b.w = fmaf(v1, wA[u+1].w, b.w);
        }
        if (k + 8 < 128) {
            #pragma unroll
            for (int u = 0; u < 4; ++u) wA[u] = *(const float4*)(Wc + (k + 8 + u) * H_);
        }
        #pragma unroll
        for (int u = 0; u < 4; u += 2) {
            float v0 = act[n][k + 4 + u], v1 = act[n][k + 4 + u + 1];
            a.x = fmaf(v0, wB[u].x, a.x);     a.y = fmaf(v0, wB[u].y, a.y);
            a.z = fmaf(v0, wB[u].z, a.z);     a.w = fmaf(v0, wB[u].w, a.w);
            b.x = fmaf(v1, wB[u+1].x, b.x);   b.y = fmaf(v1, wB[u+1].y, b.y);
            b.z = fmaf(v1, wB[u+1].z, b.z);   b.w = fmaf(v1, wB[u+1].w, b.w);
        }
    }
    float4 r; r.x = a.x + b.x; r.y = a.y + b.y; r.z = a.z + b.z; r.w = a.w + b.w;
    if (bias) {
        float4 bv = *(const float4*)(bias + c0);
        r.x += bv.x; r.y += bv.y; r.z += bv.z; r.w += bv.w;
    }
    *(float4*)(op + (size_t)(node0 + n) * H_ + c0) = r;
}

// ---------------------------------------------------------------------------
// K2: S[i][c] = sum_j m_j * silu(P[i][c] + Q[j][c] + d_ij*wd[c])
// grid 512 (4 i/block), block 512: c = t&127, j-quarter jq = t>>7 (64 j each).
// 16 waves/CU; Q loads 8-deep ping-pong pipelined.
// ---------------------------------------------------------------------------
__global__ __launch_bounds__(512) void k2(
    const float* __restrict__ P, const float* __restrict__ Q,
    const float* __restrict__ We1, const float* __restrict__ positions,
    const float* __restrict__ mask, float* __restrict__ S)
{
    __shared__ float dls[256][4];
    __shared__ float mls[256];
    __shared__ float part[4][4][128];
    const int t  = threadIdx.x;
    const int b  = blockIdx.x >> 6;
    const int i0 = (blockIdx.x & 63) * 4;

    if (t < 256) mls[t] = mask[b * N_ + t];
    {
        const int t2 = t & 255;
        const int half = t >> 8;
        const int il = t2 & 3;
        const int jb = t2 >> 2;
        const float* pb = positions + b * N_ * 3;
        const float pix = pb[(i0 + il) * 3 + 0];
        const float piy = pb[(i0 + il) * 3 + 1];
        const float piz = pb[(i0 + il) * 3 + 2];
        #pragma unroll
        for (int s = 0; s < 2; ++s) {
            int j = jb + 64 * (half * 2 + s);
            float dx = pix - pb[j * 3 + 0];
            float dy = piy - pb[j * 3 + 1];
            float dz = piz - pb[j * 3 + 2];
            float sq = dx * dx + dy * dy + dz * dz;
            dls[j][il] = (sq > 0.f) ? sqrtf(sq) : 0.f;
        }
    }
    __syncthreads();
    const int c  = t & 127;
    const int jq = t >> 7;
    const float wdc   = We1[256 * H_ + c];
    const float base0 = P[(size_t)(b * N_ + i0 + 0) * H_ + c];
    const float base1 = P[(size_t)(b * N_ + i0 + 1) * H_ + c];
    const float base2 = P[(size_t)(b * N_ + i0 + 2) * H_ + c];
    const float base3 = P[(size_t)(b * N_ + i0 + 3) * H_ + c];
    float acc0 = 0.f, acc1 = 0.f, acc2 = 0.f, acc3 = 0.f;
    const float* __restrict__ Qb = Q + (size_t)(b * N_ + jq * 64) * H_ + c;

    float qA[8], qB[8];
    #pragma unroll
    for (int u = 0; u < 8; ++u) qA[u] = Qb[u * H_];

    #pragma unroll
    for (int jj = 0; jj < 64; jj += 16) {
        #pragma unroll
        for (int u = 0; u < 8; ++u) qB[u] = Qb[(jj + 8 + u) * H_];
        #pragma unroll
        for (int u = 0; u < 8; ++u) {
            const int j = jq * 64 + jj + u;
            float mj = mls[j];
            float4 d4 = *(const float4*)(&dls[j][0]);
            float x0 = fmaf(d4.x, wdc, base0 + qA[u]);
            float x1 = fmaf(d4.y, wdc, base1 + qA[u]);
            float x2 = fmaf(d4.z, wdc, base2 + qA[u]);
            float x3 = fmaf(d4.w, wdc, base3 + qA[u]);
            acc0 = fmaf(silu_fast(x0), mj, acc0);
            acc1 = fmaf(silu_fast(x1), mj, acc1);
            acc2 = fmaf(silu_fast(x2), mj, acc2);
            acc3 = fmaf(silu_fast(x3), mj, acc3);
        }
        if (jj + 16 < 64) {
            #pragma unroll
            for (int u = 0; u < 8; ++u) qA[u] = Qb[(jj + 16 + u) * H_];
        }
        #pragma unroll
        for (int u = 0; u < 8; ++u) {
            const int j = jq * 64 + jj + 8 + u;
            float mj = mls[j];
            float4 d4 = *(const float4*)(&dls[j][0]);
            float x0 = fmaf(d4.x, wdc, base0 + qB[u]);
            float x1 = fmaf(d4.y, wdc, base1 + qB[u]);
            float x2 = fmaf(d4.z, wdc, base2 + qB[u]);
            float x3 = fmaf(d4.w, wdc, base3 + qB[u]);
            acc0 = fmaf(silu_fast(x0), mj, acc0);
            acc1 = fmaf(silu_fast(x1), mj, acc1);
            acc2 = fmaf(silu_fast(x2), mj, acc2);
            acc3 = fmaf(silu_fast(x3), mj, acc3);
        }
    }
    part[jq][0][c] = acc0; part[jq][1][c] = acc1;
    part[jq][2][c] = acc2; part[jq][3][c] = acc3;
    __syncthreads();
    {
        const int il = t >> 7;
        const int cc = t & 127;
        S[(size_t)(b * N_ + i0 + il) * H_ + cc] =
            (part[0][il][cc] + part[1][il][cc]) + (part[2][il][cc] + part[3][il][cc]);
    }
}

// ---------------------------------------------------------------------------
// K3: fused node pipeline (per-node local): agg -> hidden -> out.
// grid 1024 (2 nodes/block), block 256: n = t>>7, c = t&127. 16 waves/CU.
// ---------------------------------------------------------------------------
__global__ __launch_bounds__(256) void k3(
    const float* __restrict__ S, const float* __restrict__ pre,
    const float* __restrict__ node, const float* __restrict__ mask,
    const float* __restrict__ We2, const float* __restrict__ be2,
    const float* __restrict__ Wn1, const float* __restrict__ Wn2,
    const float* __restrict__ bn2, float* __restrict__ out)
{
    __shared__ float Sls[2][128], als[2][128], hls[2][128], nls[2][128];
    __shared__ float cs[4];
    const int t  = threadIdx.x;
    const int nb = blockIdx.x * 2;
    const int b  = nb >> 8;
    const int n  = t >> 7;
    const int c  = t & 127;

    Sls[n][c] = S[(size_t)(nb + n) * H_ + c];
    nls[n][c] = node[(size_t)(nb + n) * H_ + c];
    float mv = mask[b * N_ + t];
    #pragma unroll
    for (int off = 32; off >= 1; off >>= 1) mv += __shfl_down(mv, off);
    if ((t & 63) == 0) cs[t >> 6] = mv;
    __syncthreads();
    const float cnt = (cs[0] + cs[1]) + (cs[2] + cs[3]);
    const float mi  = mask[b * N_ + (nb & 255) + n];
    const float inv = mi * __builtin_amdgcn_rcpf(fmaxf(mi * cnt, 1.0f));

    // phase A: agg
    float acc = dot128(We2 + c, &Sls[n][0]);
    als[n][c] = inv * fmaf(cnt, be2[c], acc);
    __syncthreads();

    // phase B: hidden = silu(pre + agg @ Wn1[128:])
    acc = dot128(Wn1 + 128 * H_ + c, &als[n][0]);
    hls[n][c] = silu_fast(pre[(size_t)(nb + n) * H_ + c] + acc);
    __syncthreads();

    // phase C: out = node + mi * (hidden @ Wn2 + bn2)
    acc = dot128(Wn2 + c, &hls[n][0]);
    out[(size_t)(nb + n) * H_ + c] = nls[n][c] + mi * (acc + bn2[c]);
}

extern "C" void kernel_launch(void* const* d_in, const int* in_sizes, int n_in,
                              void* d_out, int out_size, void* d_ws, size_t ws_size,
                              hipStream_t stream)
{
    const float* node      = (const float*)d_in[0];
    const float* positions = (const float*)d_in[1];
    const float* mask      = (const float*)d_in[2];
    const float* We1       = (const float*)d_in[3];
    const float* be1       = (const float*)d_in[4];
    const float* We2       = (const float*)d_in[5];
    const float* be2       = (const float*)d_in[6];
    const float* Wn1       = (const float*)d_in[7];
    const float* bn1       = (const float*)d_in[8];
    const float* Wn2       = (const float*)d_in[9];
    const float* bn2       = (const float*)d_in[10];
    float* out = (float*)d_out;

    const size_t SZ = (size_t)NODES_ * H_;     // 1 MB each
    float* P   = (float*)d_ws;
    float* Q   = P + SZ;
    float* pre = Q + SZ;
    float* S   = pre + SZ;                     // peak ws = 4 MB

    k1<<<768,  256, 0, stream>>>(node, We1, be1, Wn1, bn1, P, Q, pre);
    k2<<<512,  512, 0, stream>>>(P, Q, We1, positions, mask, S);
    k3<<<1024, 256, 0, stream>>>(S, pre, node, mask, We2, be2, Wn1, Wn2, bn2, out);
}